// Round 2
// baseline (650.754 us; speedup 1.0000x reference)
//
#include <hip/hip_runtime.h>

// CategoryRouter: per-token routed 2-layer MLP head + softmax.
// B=4,S=1024 (T=4096 tokens), D=768, F=3072, V=2048, R=8.
// Strategy: group tokens by route (padded to BM), bf16 MFMA grouped GEMMs,
// fused bias/relu and bias/scatter epilogues, in-place softmax.

typedef __attribute__((ext_vector_type(8))) short    s16x8;
typedef __attribute__((ext_vector_type(4))) float    f32x4;

#define T_TOK 4096
#define D_    768
#define F_    3072
#define V_    2048
#define R_    8
#define BM    128
#define BN    128
#define BK    64
#define MAXTILES 40      // sum ceil(c_r/BM) <= 4096/128 + 8
#define PADROWS  5120    // 4096 + 8*(BM-1) rounded up to BM

// ---- workspace layout (bytes) ----
#define OFF_COUNTS  ((size_t)0)     // 8 int
#define OFF_CURS    ((size_t)64)    // 8 int
#define OFF_PADOFF  ((size_t)128)   // 9 int
#define OFF_NT      ((size_t)192)   // 1 int
#define OFF_TROUTE  ((size_t)256)   // MAXTILES int
#define OFF_TROW    ((size_t)512)   // MAXTILES int
#define OFF_TOK     ((size_t)1024)                                  // PADROWS int
#define OFF_XG      ((size_t)32768)                                 // PADROWS*D bf16
#define OFF_H       (OFF_XG  + (size_t)PADROWS*D_*2)                // PADROWS*F bf16
#define OFF_W1T     (OFF_H   + (size_t)PADROWS*F_*2)                // R*F*D bf16 ([R][F][D])
#define OFF_W2T     (OFF_W1T + (size_t)R_*F_*D_*2)                  // R*V*F bf16 ([R][V][F])

static __device__ __forceinline__ unsigned short f2bf(float f) {
  union { float f; unsigned int u; } x; x.f = f;
  unsigned int r = x.u + 0x7FFFu + ((x.u >> 16) & 1u);   // RNE
  return (unsigned short)(r >> 16);
}

// global -> LDS direct copy, 16B per lane. LDS dest must be wave-uniform
// base; HW writes base + lane*16 (m104/m108). Global src is per-lane.
static __device__ __forceinline__ void gload_lds16(const unsigned short* g,
                                                   unsigned short* l) {
  __builtin_amdgcn_global_load_lds(
      (const __attribute__((address_space(1))) unsigned int*)(const void*)g,
      (__attribute__((address_space(3))) unsigned int*)(void*)l, 16, 0, 0);
}

// ---------------- routing ----------------
__global__ void cr_count(const int* __restrict__ route, int* __restrict__ counts) {
  int t = blockIdx.x * blockDim.x + threadIdx.x;
  if (t < T_TOK) atomicAdd(&counts[route[t]], 1);
}

__global__ void cr_plan(const int* __restrict__ counts, int* __restrict__ padOff,
                        int* __restrict__ nTiles, int* __restrict__ tRoute,
                        int* __restrict__ tRow) {
  if (threadIdx.x != 0 || blockIdx.x != 0) return;
  int off = 0, tiles = 0;
  for (int r = 0; r < R_; ++r) {
    padOff[r] = off;
    int nt = (counts[r] + BM - 1) / BM;
    for (int i = 0; i < nt; ++i) { tRoute[tiles] = r; tRow[tiles] = off + i * BM; ++tiles; }
    off += nt * BM;
  }
  padOff[R_] = off;
  *nTiles = tiles;
}

// one block (192 thr) per token: claim slot, gather+convert its x row to bf16
__global__ void cr_scatter(const float* __restrict__ X, const int* __restrict__ route,
                           const int* __restrict__ padOff, int* __restrict__ curs,
                           int* __restrict__ tok, unsigned short* __restrict__ Xg) {
  __shared__ int spos;
  int t = blockIdx.x;
  if (threadIdx.x == 0) {
    int r = route[t];
    int p = padOff[r] + atomicAdd(&curs[r], 1);
    tok[p] = t;
    spos = p;
  }
  __syncthreads();
  int pos = spos;
  float4 v = reinterpret_cast<const float4*>(X + (size_t)t * D_)[threadIdx.x];
  ushort4 o;
  o.x = f2bf(v.x); o.y = f2bf(v.y); o.z = f2bf(v.z); o.w = f2bf(v.w);
  *reinterpret_cast<ushort4*>(Xg + (size_t)pos * D_ + threadIdx.x * 4) = o;
}

// ---------------- weight transpose + fp32->bf16 ----------------
// in: W [R][K][N] fp32 ; out: Wt [R][N][K] bf16   (64x64 tiles, 256 thr)
template <int K, int N>
__global__ void cr_transpose(const float* __restrict__ W, unsigned short* __restrict__ Wt) {
  __shared__ float tile[64][65];
  int r = blockIdx.z;
  const float* Wr = W + (size_t)r * K * N;
  unsigned short* Wtr = Wt + (size_t)r * N * K;
  int k0 = blockIdx.x * 64, n0 = blockIdx.y * 64;
  int t = threadIdx.x;
  int cb = (t & 15) * 4, rb = t >> 4;
#pragma unroll
  for (int i = 0; i < 4; ++i) {
    int k = rb + i * 16;
    float4 v = *reinterpret_cast<const float4*>(Wr + (size_t)(k0 + k) * N + n0 + cb);
    tile[k][cb] = v.x; tile[k][cb + 1] = v.y; tile[k][cb + 2] = v.z; tile[k][cb + 3] = v.w;
  }
  __syncthreads();
  int n = t >> 2, kc = (t & 3) * 16;
  alignas(16) unsigned short o[16];
#pragma unroll
  for (int j = 0; j < 16; ++j) o[j] = f2bf(tile[kc + j][n]);
  unsigned short* dst = Wtr + (size_t)(n0 + n) * K + k0 + kc;
  *reinterpret_cast<s16x8*>(dst)     = *reinterpret_cast<const s16x8*>(&o[0]);
  *reinterpret_cast<s16x8*>(dst + 8) = *reinterpret_cast<const s16x8*>(&o[8]);
}

// ---------------- grouped GEMM ----------------
// A [PADROWS][K] bf16 row-major; Wt [R][N][K] bf16 (K-contiguous per output col).
// MODE 0: H = relu(A@W + b)  (bf16, contiguous padded rows)
// MODE 1: out[tok[row]] = A@W + b  (fp32 scatter)
// m97-verified structure: 128x128 tile, BK=64, global_load_lds w16, 2-barrier.
template <int K, int N, int MODE>
__global__ __launch_bounds__(256) void cr_gemm(
    const unsigned short* __restrict__ A, const unsigned short* __restrict__ Wt,
    const float* __restrict__ bias, const int* __restrict__ nTiles,
    const int* __restrict__ tRoute, const int* __restrict__ tRow,
    const int* __restrict__ tok, unsigned short* __restrict__ Hout,
    float* __restrict__ Fout) {
  int mt = blockIdx.x;
  if (mt >= *nTiles) return;
  int route = tRoute[mt], row0 = tRow[mt];
  int col0 = blockIdx.y * BN;
  const unsigned short* Ag = A + (size_t)row0 * K;
  const unsigned short* Bg = Wt + ((size_t)route * N + col0) * K;

  __shared__ __align__(16) unsigned short As[BM * BK];  // [row][k]
  __shared__ __align__(16) unsigned short Bs[BN * BK];  // [col][k]

  int tid = threadIdx.x, lane = tid & 63, w = tid >> 6;
  int wr = w >> 1, wc = w & 1;
  int srow = lane >> 3;          // row within 8-row chunk (staging)
  int scol = (lane & 7) * 8;     // k element within BK (staging)
  int frow = lane & 15;          // fragment row/col
  int fk   = (lane >> 4) * 8;    // fragment k base

  f32x4 acc[4][4] = {};

  for (int kt = 0; kt < K; kt += BK) {
#pragma unroll
    for (int j = 0; j < 4; ++j) {
      int chunk = j * 4 + w;                 // wave-uniform
      int rrow = chunk * 8 + srow;           // 0..127
      gload_lds16(Ag + (size_t)rrow * K + kt + scol, As + chunk * 512);
      gload_lds16(Bg + (size_t)rrow * K + kt + scol, Bs + chunk * 512);
    }
    __syncthreads();
#pragma unroll
    for (int kk = 0; kk < 2; ++kk) {
      s16x8 a[4], b[4];
#pragma unroll
      for (int mi = 0; mi < 4; ++mi)
        a[mi] = *reinterpret_cast<const s16x8*>(&As[(wr * 64 + mi * 16 + frow) * BK + kk * 32 + fk]);
#pragma unroll
      for (int ni = 0; ni < 4; ++ni)
        b[ni] = *reinterpret_cast<const s16x8*>(&Bs[(wc * 64 + ni * 16 + frow) * BK + kk * 32 + fk]);
#pragma unroll
      for (int mi = 0; mi < 4; ++mi)
#pragma unroll
        for (int ni = 0; ni < 4; ++ni)
          acc[mi][ni] = __builtin_amdgcn_mfma_f32_16x16x32_bf16(a[mi], b[ni], acc[mi][ni], 0, 0, 0);
    }
    __syncthreads();
  }

  // epilogue: C/D layout col=lane&15, row=(lane>>4)*4+j  (m89/m91-verified)
  int crow = (lane >> 4) * 4;
  int ccol = lane & 15;
#pragma unroll
  for (int mi = 0; mi < 4; ++mi) {
#pragma unroll
    for (int ni = 0; ni < 4; ++ni) {
      int gcol = col0 + wc * 64 + ni * 16 + ccol;
      float bv = bias[(size_t)route * N + gcol];
#pragma unroll
      for (int j = 0; j < 4; ++j) {
        int prow = row0 + wr * 64 + mi * 16 + crow + j;
        float v = acc[mi][ni][j] + bv;
        if (MODE == 0) {
          v = fmaxf(v, 0.f);
          Hout[(size_t)prow * N + gcol] = f2bf(v);
        } else {
          int tk = tok[prow];
          if (tk >= 0) Fout[(size_t)tk * N + gcol] = v;
        }
      }
    }
  }
}

// ---------------- softmax (in place over V=2048, one block per token) ----------
__global__ void cr_softmax(float* __restrict__ out) {
  int row = blockIdx.x;
  float* p = out + (size_t)row * V_;
  int t = threadIdx.x;
  float4 v0 = reinterpret_cast<float4*>(p)[t];
  float4 v1 = reinterpret_cast<float4*>(p)[t + 256];
  float m = fmaxf(fmaxf(fmaxf(v0.x, v0.y), fmaxf(v0.z, v0.w)),
                  fmaxf(fmaxf(v1.x, v1.y), fmaxf(v1.z, v1.w)));
#pragma unroll
  for (int o = 32; o; o >>= 1) m = fmaxf(m, __shfl_xor(m, o));
  __shared__ float sm[4], ss[4];
  int w = t >> 6;
  if ((t & 63) == 0) sm[w] = m;
  __syncthreads();
  m = fmaxf(fmaxf(sm[0], sm[1]), fmaxf(sm[2], sm[3]));
  v0.x = expf(v0.x - m); v0.y = expf(v0.y - m); v0.z = expf(v0.z - m); v0.w = expf(v0.w - m);
  v1.x = expf(v1.x - m); v1.y = expf(v1.y - m); v1.z = expf(v1.z - m); v1.w = expf(v1.w - m);
  float s = v0.x + v0.y + v0.z + v0.w + v1.x + v1.y + v1.z + v1.w;
#pragma unroll
  for (int o = 32; o; o >>= 1) s += __shfl_xor(s, o);
  if ((t & 63) == 0) ss[w] = s;
  __syncthreads();
  s = ss[0] + ss[1] + ss[2] + ss[3];
  float inv = 1.f / s;
  v0.x *= inv; v0.y *= inv; v0.z *= inv; v0.w *= inv;
  v1.x *= inv; v1.y *= inv; v1.z *= inv; v1.w *= inv;
  reinterpret_cast<float4*>(p)[t] = v0;
  reinterpret_cast<float4*>(p)[t + 256] = v1;
}

extern "C" void kernel_launch(void* const* d_in, const int* in_sizes, int n_in,
                              void* d_out, int out_size, void* d_ws, size_t ws_size,
                              hipStream_t stream) {
  const float* X      = (const float*)d_in[0];
  const int*   route  = (const int*)d_in[1];
  const float* W1     = (const float*)d_in[2];
  const float* b1     = (const float*)d_in[3];
  const float* W2     = (const float*)d_in[4];
  const float* b2     = (const float*)d_in[5];
  float*       out    = (float*)d_out;
  char*        ws     = (char*)d_ws;

  int* counts = (int*)(ws + OFF_COUNTS);
  int* curs   = (int*)(ws + OFF_CURS);
  int* padOff = (int*)(ws + OFF_PADOFF);
  int* nT     = (int*)(ws + OFF_NT);
  int* tRoute = (int*)(ws + OFF_TROUTE);
  int* tRow   = (int*)(ws + OFF_TROW);
  int* tok    = (int*)(ws + OFF_TOK);
  unsigned short* Xg  = (unsigned short*)(ws + OFF_XG);
  unsigned short* H   = (unsigned short*)(ws + OFF_H);
  unsigned short* W1T = (unsigned short*)(ws + OFF_W1T);
  unsigned short* W2T = (unsigned short*)(ws + OFF_W2T);

  hipMemsetAsync(ws, 0, 1024, stream);                              // counters/meta
  hipMemsetAsync(ws + OFF_TOK, 0xFF, (size_t)PADROWS * 4, stream);  // tok = -1
  hipMemsetAsync(ws + OFF_XG, 0, (size_t)PADROWS * D_ * 2, stream); // zero padding rows

  cr_count<<<T_TOK / 256, 256, 0, stream>>>(route, counts);
  cr_plan<<<1, 64, 0, stream>>>(counts, padOff, nT, tRoute, tRow);
  cr_scatter<<<T_TOK, 192, 0, stream>>>(X, route, padOff, curs, tok, Xg);

  cr_transpose<D_, F_><<<dim3(D_ / 64, F_ / 64, R_), 256, 0, stream>>>(W1, W1T);
  cr_transpose<F_, V_><<<dim3(F_ / 64, V_ / 64, R_), 256, 0, stream>>>(W2, W2T);

  cr_gemm<D_, F_, 0><<<dim3(MAXTILES, F_ / BN), 256, 0, stream>>>(
      Xg, W1T, b1, nT, tRoute, tRow, tok, H, nullptr);
  cr_gemm<F_, V_, 1><<<dim3(MAXTILES, V_ / BN), 256, 0, stream>>>(
      H, W2T, b2, nT, tRoute, tRow, tok, nullptr, out);

  cr_softmax<<<T_TOK, 256, 0, stream>>>(out);
}